// Round 3
// baseline (662.400 us; speedup 1.0000x reference)
//
#include <hip/hip_runtime.h>

// UnfoldTransposeNd: x (16,64,64,64) f32 -> out (16, 576, 128*128) f32
// out[b, c*9 + jh*3 + jw, oh, ow] = x[b, c, ih, iw]
//   rh = oh+1-jh must be >=0, even, ih = rh/2 < 64
//   rw = ow+1-jw must be >=0, even, iw = rw/2 < 64
//
// Wave-per-(cc,j) decomposition:
//   - valid ow's within a row have fixed parity p = (1-jw)&1
//   - lane l covers the float2 at ow = 2l; its (sole possible) source is
//       x[cc, ih, l + dlt], dlt = (jw==0), valid iff l+dlt < 64
//   - wave loops oh = 0..127: one coalesced 256B load + one 512B store
//   Each wave streams a contiguous 64KB output region. 9216 waves total.

__global__ __launch_bounds__(256) void unfold_t2d_kernel(
    const float* __restrict__ x, float* __restrict__ out) {
    int lane = threadIdx.x & 63;
    int wid  = blockIdx.x * 4 + (threadIdx.x >> 6);   // 0..9215 = (b*C+c)*9 + j
    int cc   = wid / 9;
    int j    = wid - cc * 9;
    int jh   = j / 3;
    int jw   = j - jh * 3;
    int p    = (1 - jw) & 1;        // parity of valid ow within the row
    int dlt  = (jw == 0) ? 1 : 0;   // input-column shift for this j
    int iwl  = lane + dlt;          // this lane's input column
    bool wv  = iwl < 64;            // lane 63 invalid when jw==0

    const float* xc = x + cc * 4096;                       // x[b,c,:,:]
    float2* ob = reinterpret_cast<float2*>(out + ((size_t)wid << 14)) + lane;

#pragma unroll 4
    for (int oh = 0; oh < 128; ++oh) {
        int rh = oh + 1 - jh;
        int ih = rh >> 1;
        bool hv = (rh >= 0) & ((rh & 1) == 0) & (ih < 64);
        float v = 0.f;
        if (hv & wv) v = xc[ih * 64 + iwl];
        float2 o;
        o.x = (p == 0) ? v : 0.f;
        o.y = (p == 1) ? v : 0.f;
        ob[(size_t)oh * 64] = o;
    }
}

extern "C" void kernel_launch(void* const* d_in, const int* in_sizes, int n_in,
                              void* d_out, int out_size, void* d_ws, size_t ws_size,
                              hipStream_t stream) {
    const float* x = (const float*)d_in[0];
    float* out = (float*)d_out;
    // 16*64 channels * 9 taps = 9216 waves; 4 waves/block -> 2304 blocks
    unfold_t2d_kernel<<<2304, 256, 0, stream>>>(x, out);
}

// Round 4
// 601.255 us; speedup vs baseline: 1.1017x; 1.1017x over previous
//
#include <hip/hip_runtime.h>

// UnfoldTransposeNd: x (16,64,64,64) f32 -> out (16, 576, 128, 128) f32
// out[b, c*9 + jh*3 + jw, oh, ow] = x[b, c, rh/2, rw/2]
//   rh = oh+1-jh: >=0, even, rh/2 < 64;  rw = ow+1-jw: >=0, even, rw/2 < 64
//
// Block = (channel cc, oh-half h). Stage x[cc] (16 KB) in LDS once, then
// stream 9 x 32 KB output regions as coalesced float4 stores fed from LDS.
// Per float4 at (oh, ow0=4*fw): valid elements have parity p=(1-jw)&1 and
// source words colw=2*fw+dlt, colw+1 (dlt = jw==0). Element (jw==0, fw==31,
// e=3) falls off the row -> 0 (LDS padded so the dead read stays in bounds).

__global__ __launch_bounds__(256) void unfold_t2d_kernel(
    const float* __restrict__ x, float* __restrict__ out) {
    __shared__ float lds[64 * 64 + 68];   // +68 pad covers dead edge read
    int tid = threadIdx.x;
    int bid = blockIdx.x;                 // 0..2047
    int cc  = bid >> 1;                   // b*C + c
    int h   = bid & 1;                    // oh half: rows [64h, 64h+64)

    // stage x[cc,:,:] (4096 floats) into LDS
    const float4* xs = reinterpret_cast<const float4*>(x + cc * 4096);
    float4* ls = reinterpret_cast<float4*>(lds);
#pragma unroll
    for (int i = 0; i < 4; ++i) ls[i * 256 + tid] = xs[i * 256 + tid];
    __syncthreads();

    int fw = tid & 31;                    // float4 column within output row
    int rb = tid >> 5;                    // row sub-index 0..7
    float4* outb = reinterpret_cast<float4*>(out)
                 + (size_t)cc * 9 * 4096 + h * 2048;

#pragma unroll
    for (int j = 0; j < 9; ++j) {
        const int jh  = j / 3, jw = j % 3;      // compile-time (unrolled)
        const int dlt = (jw == 0) ? 1 : 0;
        const int p   = (1 - jw) & 1;           // parity of valid ow
        int  colw = 2 * fw + dlt;               // LDS word column
        bool edge = (jw == 0) && (fw == 31);    // second source word off-row
        float4* oj = outb + j * 4096;
#pragma unroll
        for (int it = 0; it < 8; ++it) {
            int oh = h * 64 + it * 8 + rb;
            int rh = oh + 1 - jh;
            int ih = rh >> 1;
            bool hv = (rh >= 0) & ((rh & 1) == 0) & (ih < 64);
            int ihc = hv ? ih : 0;              // clamp for safe LDS read
            int base = ihc * 64 + colw;
            float sx = lds[base];
            float sy = lds[base + 1];
            sx = hv ? sx : 0.f;
            sy = (hv && !edge) ? sy : 0.f;
            float4 o;
            if (p == 0) { o.x = sx;  o.y = 0.f; o.z = sy;  o.w = 0.f; }
            else        { o.x = 0.f; o.y = sx;  o.z = 0.f; o.w = sy;  }
            oj[it * 256 + tid] = o;
        }
    }
}

extern "C" void kernel_launch(void* const* d_in, const int* in_sizes, int n_in,
                              void* d_out, int out_size, void* d_ws, size_t ws_size,
                              hipStream_t stream) {
    const float* x = (const float*)d_in[0];
    float* out = (float*)d_out;
    // 1024 channels x 2 oh-halves = 2048 blocks, 256 threads (4 waves)
    unfold_t2d_kernel<<<2048, 256, 0, stream>>>(x, out);
}